// Round 8
// baseline (70.757 us; speedup 1.0000x reference)
//
#include <hip/hip_runtime.h>

// SO(3) exp map (Rodrigues) + translation -> 4x4 matrix.
// Input:  x[B][6] f32  (w = x[:,0:3], t = x[:,3:6])
// Output: out[B][4][4] f32 row-major.
//
// R7 winner (56.2us, 6.26 TB/s): LDS-staged coalesced float4 stores +
// non-temporal output stores + hw transcendentals.
// This round: (a) non-temporal INPUT loads (read-once stream, evict-first,
// no L2 churn on the read path; same-wave back-to-back consumers so no
// re-fetch risk), (b) balanced grid: 1954 blocks -> 1953 do exactly 8
// tiles (vs 2048 blocks doing 7.63 avg with a 13% ragged tail).

#define TPB 256
#define P4 258  // padded row length (float4) for the LDS transpose buffer

typedef float vfloat4 __attribute__((ext_vector_type(4)));
typedef float vfloat2 __attribute__((ext_vector_type(2)));

__global__ void __launch_bounds__(TPB)
so3_to_mat_kernel(const float* __restrict__ x, float* __restrict__ out, int n) {
    __shared__ vfloat4 buf[4 * P4];  // buf[s*P4 + r] = float4 #s of tile-row r
    const int t = threadIdx.x;
    const int ntiles = (n + TPB - 1) / TPB;

    for (int tile = blockIdx.x; tile < ntiles; tile += gridDim.x) {
        const int base = tile * TPB;
        const int row = base + t;

        if (row < n) {
            // Row occupies 24 B at x + 6*row; 8-B aligned -> three nt float2 loads.
            const vfloat2* xr = reinterpret_cast<const vfloat2*>(x) + 3 * (size_t)row;
            const vfloat2 p0 = __builtin_nontemporal_load(xr + 0);
            const vfloat2 p1 = __builtin_nontemporal_load(xr + 1);
            const vfloat2 p2 = __builtin_nontemporal_load(xr + 2);
            const float wx = p0.x, wy = p0.y, wz = p1.x;
            const float tx = p1.y, ty = p2.x, tz = p2.y;

            const float t2 = wx * wx + wy * wy + wz * wz;
            const bool small = t2 < 1e-8f;

            // Fast reciprocals / sqrt via transcendental pipe.
            const float inv_th = __builtin_amdgcn_rsqf(small ? 1.0f : t2); // 1/theta
            const float inv_t2 = __builtin_amdgcn_rcpf(t2);                 // 1/theta^2
            const float th = (small ? 1.0f : t2) * inv_th;                  // theta

            const float s = __sinf(th);
            const float c = __cosf(th);

            const float A  = small ? (1.0f - t2 * (1.0f / 6.0f))  : (s * inv_th);
            const float Bc = small ? (0.5f - t2 * (1.0f / 24.0f)) : ((1.0f - c) * inv_t2);

            const float xx = wx * wx, yy = wy * wy, zz = wz * wz;
            const float xy = wx * wy, xz = wx * wz, yz = wy * wz;

            {
                vfloat4 v;
                v.x = 1.0f - Bc * (yy + zz); v.y = -A * wz + Bc * xy;
                v.z =  A * wy + Bc * xz;     v.w = tx;
                buf[0 * P4 + t] = v;
            }
            {
                vfloat4 v;
                v.x =  A * wz + Bc * xy;     v.y = 1.0f - Bc * (xx + zz);
                v.z = -A * wx + Bc * yz;     v.w = ty;
                buf[1 * P4 + t] = v;
            }
            {
                vfloat4 v;
                v.x = -A * wy + Bc * xz;     v.y =  A * wx + Bc * yz;
                v.z = 1.0f - Bc * (xx + yy); v.w = tz;
                buf[2 * P4 + t] = v;
            }
            {
                vfloat4 v;
                v.x = 0.0f; v.y = 0.0f; v.z = 0.0f; v.w = 1.0f;
                buf[3 * P4 + t] = v;
            }
        }
        __syncthreads();

        // Coalesced write-out: 256 rows * 4 float4 = 1024 lane-consecutive
        // float4, streamed with non-temporal stores (no L2/L3 allocation).
        const int nrow = min(TPB, n - base);
        vfloat4* ob = reinterpret_cast<vfloat4*>(out) + 4 * (size_t)base;
        #pragma unroll
        for (int m = 0; m < 4; ++m) {
            const int g = t + TPB * m;
            if (g < 4 * nrow) {
                __builtin_nontemporal_store(buf[(g & 3) * P4 + (g >> 2)], &ob[g]);
            }
        }
        __syncthreads();  // protect LDS before next tile's writes
    }
}

extern "C" void kernel_launch(void* const* d_in, const int* in_sizes, int n_in,
                              void* d_out, int out_size, void* d_ws, size_t ws_size,
                              hipStream_t stream) {
    const float* x = (const float*)d_in[0];
    float* out = (float*)d_out;
    const int n = in_sizes[0] / 6;  // 4,000,000 rows

    const int ntiles = (n + TPB - 1) / TPB;   // 15625
    // Balanced grid: 1954 blocks -> 1953 blocks get exactly 8 tiles each
    // (15624 tiles) + 1 block gets the last tile. Still ~7.6 blocks/CU.
    int grid = ntiles < 1954 ? ntiles : 1954;

    so3_to_mat_kernel<<<grid, TPB, 0, stream>>>(x, out, n);
}

// Round 9
// 55.832 us; speedup vs baseline: 1.2673x; 1.2673x over previous
//
#include <hip/hip_runtime.h>

// SO(3) exp map (Rodrigues) + translation -> 4x4 matrix.
// Input:  x[B][6] f32  (w = x[:,0:3], t = x[:,3:6])
// Output: out[B][4][4] f32 row-major.
//
// EXACT revert to the round-7 winner (56.2us, 6.26 TB/s = 99.5% of the
// measured 6.29 TB/s copy ceiling):
//   - LDS-staged, fully-coalesced lane-consecutive float4 stores
//   - NON-TEMPORAL stores (output is write-once; avoids L2/L3
//     write-allocate churn): 68.7 -> 56.2us
//   - REGULAR (cached) input loads: the 3x float2-per-lane stride-24
//     pattern reuses each cache line across 3 instructions; R8 showed
//     nt loads re-fetch and cost +14us. Do NOT nt the read stream.
//   - hw transcendentals (v_sin/v_cos/v_rsq/v_rcp)
//   - grid 2048 = exactly 8 blocks/CU

#define TPB 256
#define P4 258  // padded row length (float4) for the LDS transpose buffer

typedef float vfloat4 __attribute__((ext_vector_type(4)));

__global__ void __launch_bounds__(TPB)
so3_to_mat_kernel(const float* __restrict__ x, float* __restrict__ out, int n) {
    __shared__ vfloat4 buf[4 * P4];  // buf[s*P4 + r] = float4 #s of tile-row r
    const int t = threadIdx.x;
    const int ntiles = (n + TPB - 1) / TPB;

    for (int tile = blockIdx.x; tile < ntiles; tile += gridDim.x) {
        const int base = tile * TPB;
        const int row = base + t;

        if (row < n) {
            // Row occupies 24 B at x + 6*row; 8-B aligned -> three float2 loads.
            const float2* xr = reinterpret_cast<const float2*>(x) + 3 * (size_t)row;
            const float2 p0 = xr[0];
            const float2 p1 = xr[1];
            const float2 p2 = xr[2];
            const float wx = p0.x, wy = p0.y, wz = p1.x;
            const float tx = p1.y, ty = p2.x, tz = p2.y;

            const float t2 = wx * wx + wy * wy + wz * wz;
            const bool small = t2 < 1e-8f;

            // Fast reciprocals / sqrt via transcendental pipe.
            const float inv_th = __builtin_amdgcn_rsqf(small ? 1.0f : t2); // 1/theta
            const float inv_t2 = __builtin_amdgcn_rcpf(t2);                 // 1/theta^2
            const float th = (small ? 1.0f : t2) * inv_th;                  // theta

            const float s = __sinf(th);
            const float c = __cosf(th);

            const float A  = small ? (1.0f - t2 * (1.0f / 6.0f))  : (s * inv_th);
            const float Bc = small ? (0.5f - t2 * (1.0f / 24.0f)) : ((1.0f - c) * inv_t2);

            const float xx = wx * wx, yy = wy * wy, zz = wz * wz;
            const float xy = wx * wy, xz = wx * wz, yz = wy * wz;

            {
                vfloat4 v;
                v.x = 1.0f - Bc * (yy + zz); v.y = -A * wz + Bc * xy;
                v.z =  A * wy + Bc * xz;     v.w = tx;
                buf[0 * P4 + t] = v;
            }
            {
                vfloat4 v;
                v.x =  A * wz + Bc * xy;     v.y = 1.0f - Bc * (xx + zz);
                v.z = -A * wx + Bc * yz;     v.w = ty;
                buf[1 * P4 + t] = v;
            }
            {
                vfloat4 v;
                v.x = -A * wy + Bc * xz;     v.y =  A * wx + Bc * yz;
                v.z = 1.0f - Bc * (xx + yy); v.w = tz;
                buf[2 * P4 + t] = v;
            }
            {
                vfloat4 v;
                v.x = 0.0f; v.y = 0.0f; v.z = 0.0f; v.w = 1.0f;
                buf[3 * P4 + t] = v;
            }
        }
        __syncthreads();

        // Coalesced write-out: 256 rows * 4 float4 = 1024 lane-consecutive
        // float4, streamed with non-temporal stores (no L2/L3 allocation).
        const int nrow = min(TPB, n - base);
        vfloat4* ob = reinterpret_cast<vfloat4*>(out) + 4 * (size_t)base;
        #pragma unroll
        for (int m = 0; m < 4; ++m) {
            const int g = t + TPB * m;
            if (g < 4 * nrow) {
                __builtin_nontemporal_store(buf[(g & 3) * P4 + (g >> 2)], &ob[g]);
            }
        }
        __syncthreads();  // protect LDS before next tile's writes
    }
}

extern "C" void kernel_launch(void* const* d_in, const int* in_sizes, int n_in,
                              void* d_out, int out_size, void* d_ws, size_t ws_size,
                              hipStream_t stream) {
    const float* x = (const float*)d_in[0];
    float* out = (float*)d_out;
    const int n = in_sizes[0] / 6;  // 4,000,000 rows

    const int ntiles = (n + TPB - 1) / TPB;
    int grid = ntiles < 2048 ? ntiles : 2048;  // exactly 8 blocks/CU

    so3_to_mat_kernel<<<grid, TPB, 0, stream>>>(x, out, n);
}